// Round 7
// baseline (399.230 us; speedup 1.0000x reference)
//
#include <hip/hip_runtime.h>

// NLQR: NB=1024, T=128, NS=12, NC=4, N=16.
// Round 7: ATTRIBUTION SPLIT. Backward and forward become separate kernels
// with logic identical to R6 (validated, 208 us fused) so rocprof reports
// per-phase dur/counters. Forward reads u from global us_out (4-deep
// prefetch) instead of the LDS stash; backward is byte-identical minus the
// forward section and the uL stash.

#define NBQ 1024
#define TT  128

__device__ __forceinline__ float dotf4(float4 a, float4 b) {
  return a.x*b.x + a.y*b.y + a.z*b.z + a.w*b.w;
}
__device__ __forceinline__ float dpp_qx1(float x) {  // quad_perm [1,0,3,2]
  return __int_as_float(__builtin_amdgcn_mov_dpp(__float_as_int(x), 0xB1, 0xF, 0xF, true));
}
__device__ __forceinline__ float dpp_qx2(float x) {  // quad_perm [2,3,0,1]
  return __int_as_float(__builtin_amdgcn_mov_dpp(__float_as_int(x), 0x4E, 0xF, 0xF, true));
}
template<int Q> __device__ __forceinline__ float4 bcast4(float4 v) {
  float4 r;
  r.x = __int_as_float(__builtin_amdgcn_mov_dpp(__float_as_int(v.x), Q*0x55, 0xF, 0xF, true));
  r.y = __int_as_float(__builtin_amdgcn_mov_dpp(__float_as_int(v.y), Q*0x55, 0xF, 0xF, true));
  r.z = __int_as_float(__builtin_amdgcn_mov_dpp(__float_as_int(v.z), Q*0x55, 0xF, 0xF, true));
  r.w = __int_as_float(__builtin_amdgcn_mov_dpp(__float_as_int(v.w), Q*0x55, 0xF, 0xF, true));
  return r;
}

#define MKS(K, O, MY)  { float4 mk_ = bcast4<O>(MY);                           \
  qt4_.x += gk_[K]*mk_.x; qt4_.y += gk_[K]*mk_.y;                              \
  qt4_.z += gk_[K]*mk_.z; qt4_.w += gk_[K]*mk_.w; }

#define BW_BODY(T_, QV, PV, CV, P0,P1,P2,P3, S0,S1,S2,S3)                      \
{                                                                              \
  const int  t_   = (T_);                                                      \
  const long bt_  = b*TT + t_;                                                 \
  const long btL_ = b*TT + ((t_ >= 4) ? (t_ - 4) : 0);                         \
  float4 qN_ = *(const float4*)(Qg + btL_*256 + qoff);                         \
  const float* fpL_ = lt48 ? (Ag + btL_*144 + l) : (Bg + btL_*48 + bm_);       \
  float fN0_ = fpL_[0], fN1_ = fpL_[fstr_], fN2_ = fpL_[2*fstr_], fN3_ = fpL_[foff3];  \
  float  pN_ = pg[btL_*16 + j];                                                \
  float  cN_ = cug[btL_*4 + q4];                                               \
  float* FTc_ = (t_ & 1) ? FT1 : FT0;                                          \
  float* FTn_ = (t_ & 1) ? FT0 : FT1;                                          \
  if (lt48)      { FTn_[ba] = P0; FTn_[ba+4] = P1; FTn_[ba+8] = P2; }          \
  else if (lt60) { FTn_[bb] = P0; FTn_[bb+3] = P1; FTn_[bb+6] = P2; FTn_[bb+9] = P3; } \
  const float4* fj4_ = (const float4*)(FTc_ + j*12);                           \
  float4 f0_=fj4_[0], f1_=fj4_[1], f2_=fj4_[2];                                \
  const float4* vrow_ = (const float4*)(Vs + (3*r + dmin)*12);                 \
  float4 mv0_=vrow_[0], mv1_=vrow_[1], mv2_=vrow_[2];                          \
  float4 mw_ = *(const float4*)(vvS + 4*dmin);                                 \
  float m0_, m1_, m2_;                                                         \
  { float4 r0_=bcast4<0>(mv0_), r1_=bcast4<0>(mv1_), r2_=bcast4<0>(mv2_);      \
    m0_ = dotf4(r0_,f0_)+dotf4(r1_,f1_)+dotf4(r2_,f2_); }                      \
  { float4 r0_=bcast4<1>(mv0_), r1_=bcast4<1>(mv1_), r2_=bcast4<1>(mv2_);      \
    m1_ = dotf4(r0_,f0_)+dotf4(r1_,f1_)+dotf4(r2_,f2_); }                      \
  { float4 r0_=bcast4<2>(mv0_), r1_=bcast4<2>(mv1_), r2_=bcast4<2>(mv2_);      \
    m2_ = dotf4(r0_,f0_)+dotf4(r1_,f1_)+dotf4(r2_,f2_); }                      \
  msh[(3*r+0)*16 + j] = m0_;                                                   \
  msh[(3*r+1)*16 + j] = m1_;                                                   \
  msh[(3*r+2)*16 + j] = m2_;                                                   \
  float qtv_;                                                                  \
  { float4 w0_=bcast4<0>(mw_), w1_=bcast4<1>(mw_), w2_=bcast4<2>(mw_);         \
    qtv_ = PV + dotf4(w0_,f0_)+dotf4(w1_,f1_)+dotf4(w2_,f2_); }                \
  float gk_[12] = {f0_.x,f0_.y,f0_.z,f0_.w, f1_.x,f1_.y,f1_.z,f1_.w,           \
                   f2_.x,f2_.y,f2_.z,f2_.w};                                   \
  float4 mys0_ = *(const float4*)(msh + (3*q4+0)*16 + cb4);                    \
  float4 mys1_ = *(const float4*)(msh + (3*q4+1)*16 + cb4);                    \
  float4 mys2_ = *(const float4*)(msh + (3*q4+2)*16 + cb4);                    \
  float4 qt4_ = QV;                                                            \
  MKS(0,0,mys0_) MKS(1,0,mys1_) MKS(2,0,mys2_)                                 \
  MKS(3,1,mys0_) MKS(4,1,mys1_) MKS(5,1,mys2_)                                 \
  MKS(6,2,mys0_) MKS(7,2,mys1_) MKS(8,2,mys2_)                                 \
  MKS(9,3,mys0_) MKS(10,3,mys1_) MKS(11,3,mys2_)                               \
  if (j >= 12)           *(float4*)(UxS + (j-12)*16 + cb4) = qt4_;             \
  if (cb == 3 && j < 12) *(float4*)(XuS + j*4) = qt4_;                         \
  if (l >= 12 && l < 16) quS[l-12] = qtv_;                                     \
  float4 myquu_ = *(const float4*)(UxS + q4*16 + 12);                          \
  float4 myux_  = *(const float4*)(UxS + q4*16 + cb4);                         \
  float4 quv_   = *(const float4*)quS;                                         \
  float4 xr_    = *(const float4*)(XuS + jc*4);                                \
  float mm_[16];                                                               \
  { float4 t0_=bcast4<0>(myquu_); mm_[0]=t0_.x; mm_[1]=t0_.y; mm_[2]=t0_.z; mm_[3]=t0_.w; \
    float4 t1_=bcast4<1>(myquu_); mm_[4]=t1_.x; mm_[5]=t1_.y; mm_[6]=t1_.z; mm_[7]=t1_.w; \
    float4 t2_=bcast4<2>(myquu_); mm_[8]=t2_.x; mm_[9]=t2_.y; mm_[10]=t2_.z; mm_[11]=t2_.w; \
    float4 t3_=bcast4<3>(myquu_); mm_[12]=t3_.x; mm_[13]=t3_.y; mm_[14]=t3_.z; mm_[15]=t3_.w; } \
  float4 ux0_=bcast4<0>(myux_), ux1_=bcast4<1>(myux_),                         \
         ux2_=bcast4<2>(myux_), ux3_=bcast4<3>(myux_);                         \
  float rdp_ = 1.0f/(mm_[0]*mm_[5] - mm_[1]*mm_[1]);                           \
  float pi00_ = mm_[5]*rdp_, pi01_ = -mm_[1]*rdp_, pi11_ = mm_[0]*rdp_;        \
  float w00_ = pi00_*mm_[2] + pi01_*mm_[6];                                    \
  float w01_ = pi00_*mm_[3] + pi01_*mm_[7];                                    \
  float w10_ = pi01_*mm_[2] + pi11_*mm_[6];                                    \
  float w11_ = pi01_*mm_[3] + pi11_*mm_[7];                                    \
  float t00_ = mm_[10] - (mm_[2]*w00_ + mm_[6]*w10_);                          \
  float t01_ = mm_[11] - (mm_[2]*w01_ + mm_[6]*w11_);                          \
  float t11_ = mm_[15] - (mm_[3]*w01_ + mm_[7]*w11_);                          \
  float rdt_ = 1.0f/(t00_*t11_ - t01_*t01_);                                   \
  float ti00_ = t11_*rdt_, ti01_ = -t01_*rdt_, ti11_ = t00_*rdt_;              \
  float u00_ = -(w00_*ti00_ + w01_*ti01_);                                     \
  float u01_ = -(w00_*ti01_ + w01_*ti11_);                                     \
  float u10_ = -(w10_*ti00_ + w11_*ti01_);                                     \
  float u11_ = -(w10_*ti01_ + w11_*ti11_);                                     \
  float i00_ = pi00_ - (u00_*w00_ + u01_*w01_);                                \
  float i01_ = pi01_ - (u00_*w10_ + u01_*w11_);                                \
  float i11_ = pi11_ - (u10_*w10_ + u11_*w11_);                                \
  float inv_[16] = { i00_, i01_, u00_, u01_,                                   \
                     i01_, i11_, u10_, u11_,                                   \
                     u00_, u10_, ti00_, ti01_,                                 \
                     u01_, u11_, ti01_, ti11_ };                               \
  float kt0_ = -(inv_[0] *quv_.x + inv_[1] *quv_.y + inv_[2] *quv_.z + inv_[3] *quv_.w); \
  float kt1_ = -(inv_[4] *quv_.x + inv_[5] *quv_.y + inv_[6] *quv_.z + inv_[7] *quv_.w); \
  float kt2_ = -(inv_[8] *quv_.x + inv_[9] *quv_.y + inv_[10]*quv_.z + inv_[11]*quv_.w); \
  float kt3_ = -(inv_[12]*quv_.x + inv_[13]*quv_.y + inv_[14]*quv_.z + inv_[15]*quv_.w); \
  float4 kc_[4];                                                               \
  _Pragma("unroll")                                                            \
  for (int c_ = 0; c_ < 4; ++c_) {                                             \
    kc_[c_].x = -(inv_[c_*4+0]*ux0_.x + inv_[c_*4+1]*ux1_.x + inv_[c_*4+2]*ux2_.x + inv_[c_*4+3]*ux3_.x); \
    kc_[c_].y = -(inv_[c_*4+0]*ux0_.y + inv_[c_*4+1]*ux1_.y + inv_[c_*4+2]*ux2_.y + inv_[c_*4+3]*ux3_.y); \
    kc_[c_].z = -(inv_[c_*4+0]*ux0_.z + inv_[c_*4+1]*ux1_.z + inv_[c_*4+2]*ux2_.z + inv_[c_*4+3]*ux3_.z); \
    kc_[c_].w = -(inv_[c_*4+0]*ux0_.w + inv_[c_*4+1]*ux1_.w + inv_[c_*4+2]*ux2_.w + inv_[c_*4+3]*ux3_.w); \
  }                                                                            \
  if (j < 12) {                                                                \
    float4 vn4_;                                                               \
    vn4_.x = qt4_.x + xr_.x*kc_[0].x + xr_.y*kc_[1].x + xr_.z*kc_[2].x + xr_.w*kc_[3].x; \
    vn4_.y = qt4_.y + xr_.x*kc_[0].y + xr_.y*kc_[1].y + xr_.z*kc_[2].y + xr_.w*kc_[3].y; \
    vn4_.z = qt4_.z + xr_.x*kc_[0].z + xr_.y*kc_[1].z + xr_.z*kc_[2].z + xr_.w*kc_[3].z; \
    vn4_.w = qt4_.w + xr_.x*kc_[0].w + xr_.y*kc_[1].w + xr_.z*kc_[2].w + xr_.w*kc_[3].w; \
    if (cb < 3) *(float4*)(Vs + j*12 + cb4) = vn4_;                            \
  }                                                                            \
  if (l < 12)                                                                  \
    vvS[l] = qtv_ + xr_.x*kt0_ + xr_.y*kt1_ + xr_.z*kt2_ + xr_.w*kt3_;         \
  float uv_ = CV + ((q4==0)?kt0_:(q4==1)?kt1_:(q4==2)?kt2_:kt3_);              \
  if (l < 4) us_out[bt_*4 + l] = uv_;                                          \
  QV = qN_; S0 = fN0_; S1 = fN1_; S2 = fN2_; S3 = fN3_; PV = pN_; CV = cN_;    \
}

__global__ __launch_bounds__(64, 1) void lqr_bw(
    const float* __restrict__ Qg, const float* __restrict__ pg,
    const float* __restrict__ Ag, const float* __restrict__ Bg,
    const float* __restrict__ cug, float* __restrict__ us_out)
{
  __shared__ __align__(16) float lds[864];
  float* FT0 = lds;        // [16][12] F^T buffer 0  (FT[n][k] = F[k][n])
  float* FT1 = lds + 192;  // [16][12] F^T buffer 1
  float* Vs  = lds + 384;  // [12][12]
  float* vvS = lds + 528;  // [12]
  float* msh = lds + 544;  // [12][16]
  float* UxS = lds + 736;  // [4][16]
  float* XuS = lds + 800;  // [12][4]
  float* quS = lds + 848;  // [4]

  const int l    = threadIdx.x;
  const int j    = l & 15;
  const int r    = l >> 4;
  const int q4   = l & 3;
  const int cb   = l >> 4;
  const int cb4  = cb << 2;
  const int dmin = (q4 < 2) ? q4 : 2;
  const int jc   = (j < 12) ? j : 11;
  const long b   = blockIdx.x;
  const bool lt48 = (l < 48);
  const bool lt60 = (l < 60);
  const int  bm_  = lt48 ? 0 : ((l - 48) % 12);
  const int  fstr_ = lt48 ? 48 : 12;
  const int  foff3 = lt48 ? 96 : 36;
  const int  ba = (l % 12) * 12 + l / 12;
  const int  bb = 144 + ((l - 48) & 3) * 12 + ((l - 48) >> 2);
  const int  qoff = j * 16 + cb4;

  if (j < 12 && cb < 3) *(float4*)(Vs + j*12 + cb4) = make_float4(0.f,0.f,0.f,0.f);
  if (l < 12) vvS[l] = 0.f;

  const long base = b*TT;
  float4 q3v,q2v,q1v,q0v;
  float  p3v,c3v,p2v,c2v,p1v,c1v,p0v,c0v;
  float  f3a,f3b,f3c,f3d, f2a,f2b,f2c,f2d, f1a,f1b,f1c,f1d, f0a,f0b,f0c,f0d;
  {
    long bt;
    bt = base+127; q3v=*(const float4*)(Qg+bt*256+qoff); p3v=pg[bt*16+j]; c3v=cug[bt*4+q4];
    { const float* fp = lt48 ? (Ag+bt*144+l) : (Bg+bt*48+bm_);
      f3a=fp[0]; f3b=fp[fstr_]; f3c=fp[2*fstr_]; f3d=fp[foff3]; }
    bt = base+126; q2v=*(const float4*)(Qg+bt*256+qoff); p2v=pg[bt*16+j]; c2v=cug[bt*4+q4];
    { const float* fp = lt48 ? (Ag+bt*144+l) : (Bg+bt*48+bm_);
      f2a=fp[0]; f2b=fp[fstr_]; f2c=fp[2*fstr_]; f2d=fp[foff3]; }
    bt = base+125; q1v=*(const float4*)(Qg+bt*256+qoff); p1v=pg[bt*16+j]; c1v=cug[bt*4+q4];
    { const float* fp = lt48 ? (Ag+bt*144+l) : (Bg+bt*48+bm_);
      f1a=fp[0]; f1b=fp[fstr_]; f1c=fp[2*fstr_]; f1d=fp[foff3]; }
    bt = base+124; q0v=*(const float4*)(Qg+bt*256+qoff); p0v=pg[bt*16+j]; c0v=cug[bt*4+q4];
    { const float* fp = lt48 ? (Ag+bt*144+l) : (Bg+bt*48+bm_);
      f0a=fp[0]; f0b=fp[fstr_]; f0c=fp[2*fstr_]; f0d=fp[foff3]; }
  }
  if (lt48)      { FT1[ba] = f3a; FT1[ba+4] = f3b; FT1[ba+8] = f3c; }
  else if (lt60) { FT1[bb] = f3a; FT1[bb+3] = f3b; FT1[bb+6] = f3c; FT1[bb+9] = f3d; }

  #pragma unroll 1
  for (int tb = TT-1; tb >= 3; tb -= 4) {
    BW_BODY(tb,   q3v, p3v, c3v,  f2a,f2b,f2c,f2d,  f3a,f3b,f3c,f3d)
    BW_BODY(tb-1, q2v, p2v, c2v,  f1a,f1b,f1c,f1d,  f2a,f2b,f2c,f2d)
    BW_BODY(tb-2, q1v, p1v, c1v,  f0a,f0b,f0c,f0d,  f1a,f1b,f1c,f1d)
    BW_BODY(tb-3, q0v, p0v, c0v,  f3a,f3b,f3c,f3d,  f0a,f0b,f0c,f0d)
  }
}

__global__ __launch_bounds__(64, 1) void lqr_fw(
    const float* __restrict__ Qg, const float* __restrict__ pg,
    const float* __restrict__ Ag, const float* __restrict__ Bg,
    const float* __restrict__ xinit, float* __restrict__ out)
{
  const int l   = threadIdx.x;
  const int q4  = l & 3;
  const int i4  = l >> 2;
  const int c0f = q4 << 2;
  const int i4c = (i4 < 12) ? i4 : 11;
  const int sl0 = (c0f+0)<<2, sl1 = (c0f+1)<<2, sl2 = (c0f+2)<<2, sl3 = (c0f+3)<<2;
  const long b  = blockIdx.x;

  float* xs_out = out;
  const float* us_in = out + (long)NBQ*TT*12;
  float* c_out  = out + (long)NBQ*TT*12 + (long)NBQ*TT*4;

  float s = xinit[b*12 + i4c];
  float cacc = 0.f;

  const long bt0 = b*TT;
  // 4-deep prefetch slots A..D
  float4 qfA, ffA, ufA, qfB, ffB, ufB, qfC, ffC, ufC, qfD, ffD, ufD;
  float  pfA, pfB, pfC, pfD;
  {
    long bt;
    bt = bt0+0; qfA=*(const float4*)(Qg+bt*256+4*l); pfA=pg[bt*16+i4];
    ffA=(q4<3)?*(const float4*)(Ag+bt*144+i4c*12+c0f):*(const float4*)(Bg+bt*48+i4c*4);
    ufA=*(const float4*)(us_in+bt*4);
    bt = bt0+1; qfB=*(const float4*)(Qg+bt*256+4*l); pfB=pg[bt*16+i4];
    ffB=(q4<3)?*(const float4*)(Ag+bt*144+i4c*12+c0f):*(const float4*)(Bg+bt*48+i4c*4);
    ufB=*(const float4*)(us_in+bt*4);
    bt = bt0+2; qfC=*(const float4*)(Qg+bt*256+4*l); pfC=pg[bt*16+i4];
    ffC=(q4<3)?*(const float4*)(Ag+bt*144+i4c*12+c0f):*(const float4*)(Bg+bt*48+i4c*4);
    ufC=*(const float4*)(us_in+bt*4);
    bt = bt0+3; qfD=*(const float4*)(Qg+bt*256+4*l); pfD=pg[bt*16+i4];
    ffD=(q4<3)?*(const float4*)(Ag+bt*144+i4c*12+c0f):*(const float4*)(Bg+bt*48+i4c*4);
    ufD=*(const float4*)(us_in+bt*4);
  }

  #pragma unroll 1
  for (int t = 0; t < TT; ++t) {
    const long btp = bt0 + ((t+4 < TT-1) ? t+4 : TT-1);
    float4 qfE = *(const float4*)(Qg + btp*256 + 4*l);
    float4 ffE = (q4 < 3) ? *(const float4*)(Ag + btp*144 + i4c*12 + c0f)
                          : *(const float4*)(Bg + btp*48  + i4c*4);
    float  pfE = pg[btp*16 + i4];
    float4 ufE = *(const float4*)(us_in + btp*4);

    float4 u4 = ufA;
    float4 xg;
    xg.x = __shfl(s, sl0, 64); xg.y = __shfl(s, sl1, 64);
    xg.z = __shfl(s, sl2, 64); xg.w = __shfl(s, sl3, 64);
    float4 xuq = (q4 < 3) ? xg : u4;
    float xui = (i4 < 12) ? s
              : (i4 == 12) ? u4.x : (i4 == 13) ? u4.y : (i4 == 14) ? u4.z : u4.w;

    if (q4 == 0 && i4 < 12) xs_out[(bt0+t)*12 + i4] = s;

    cacc += 0.5f * xui * dotf4(qfA, xuq);
    if (q4 == 0) cacc += xui * pfA;

    float zx = dotf4(ffA, xuq);
    zx += dpp_qx1(zx);
    zx += dpp_qx2(zx);
    s = zx;

    qfA = qfB; ffA = ffB; pfA = pfB; ufA = ufB;
    qfB = qfC; ffB = ffC; pfB = pfC; ufB = ufC;
    qfC = qfD; ffC = ffD; pfC = pfD; ufC = ufD;
    qfD = qfE; ffD = ffE; pfD = pfE; ufD = ufE;
  }

  cacc += __shfl_xor(cacc, 32, 64);
  cacc += __shfl_xor(cacc, 16, 64);
  cacc += __shfl_xor(cacc, 8, 64);
  cacc += __shfl_xor(cacc, 4, 64);
  cacc += dpp_qx2(cacc);
  cacc += dpp_qx1(cacc);
  if (l == 0) c_out[b] = cacc;
}

extern "C" void kernel_launch(void* const* d_in, const int* in_sizes, int n_in,
                              void* d_out, int out_size, void* d_ws, size_t ws_size,
                              hipStream_t stream) {
  const float* xinit = (const float*)d_in[0];
  // d_in[1] = current_x (unused by reference), d_in[7] = time (unused)
  const float* cu = (const float*)d_in[2];
  const float* Q  = (const float*)d_in[3];
  const float* p  = (const float*)d_in[4];
  const float* A  = (const float*)d_in[5];
  const float* Bm = (const float*)d_in[6];
  float* out = (float*)d_out;
  float* us_out = out + (long)NBQ*TT*12;

  lqr_bw<<<dim3(NBQ), dim3(64), 0, stream>>>(Q, p, A, Bm, cu, us_out);
  lqr_fw<<<dim3(NBQ), dim3(64), 0, stream>>>(Q, p, A, Bm, xinit, out);
}